// Round 17
// baseline (3806.355 us; speedup 1.0000x reference)
//
#include <hip/hip_runtime.h>
#include <hip/hip_bf16.h>

// SCAE forward on MI355X — f16 split-MFMA (Ootomo 3-product) pipeline.
//   v = h + l/2048 (f16 h,l; subnormal-guarded)  =>
//   A@B = Ah@Bh + (Ah@Bl + Al@Bh)/2048   (drop 2^-22 term)
// R17 = R16 (fused G1/G2, LDS-staged MODE1 epilogue, best 3568us) +
//  - G1 NT=2: each MODE1 block computes TWO stacked 128x128 fd-tiles
//    sharing the same B panel (384KB, L2-resident on re-stage) -> K=768
//    prologue amortized 2x (G1 ran at 975 TF vs G2's 1215 on same loop;
//    the ~20% gap is exactly its per-block fixed cost at 24 steps).
//  - topk_decode at 512 threads (parallel phases halve; decode splits
//    D=768 wave-uniformly).
// Then exact radix top-k (ties->lowest index), relu, sparse decode.

#define D_DIM 768
#define F_DIM 8192

typedef _Float16 f16;
typedef _Float16 f16x8 __attribute__((ext_vector_type(8)));
typedef float f32x4 __attribute__((ext_vector_type(4)));

#define BMN 128
#define BUFB 32768    // one K-tile: A 16KB + B 16KB (128 rows x 128B each)
#define PLNB 16384    // B region offset ([h|l] packed rows, XOR-8 swizzled)
#define EPSTRIDE 528  // epilogue LDS row stride (512B data + 16B pad)
#define LDSBYTES 69632

struct SegDesc {
    const f16 *a0, *a1, *a2, *a3;
    const f16 *b0, *b1, *b2, *b3;
    int str0, str1, str2, str3;       // A/B row stride in BYTES (= K*4)
    int steps0, steps1, steps2, steps3;
    int totalSteps;
};

__device__ inline void split_f32(float v, f16& h, f16& l) {
    float hf = (float)(f16)v;
    if (__builtin_fabsf(hf) < 6.1035156e-5f) hf = 0.f;   // keep h MFMA-normal
    h = (f16)hf;
    l = (f16)((v - hf) * 2048.0f);
}

// MODE 0: C = comb + bias[col]  (final approx; grid x=bm, y=bn)
// MODE 1: Vp = packed_split(comb * mask); NT=2 fd-tiles per block
template<int MODE>
__global__ __launch_bounds__(256, 2)
void mfma_gemm(SegDesc d, float* __restrict__ C, int ldc,
               f16* __restrict__ Vp,
               const float* __restrict__ bias,
               const unsigned char* __restrict__ conn,
               const int* __restrict__ flagp)
{
    __shared__ char lds[LDSBYTES];   // K-loop: 2x32KB dbuf; epilogue: tile
    const int tid = threadIdx.x;
    int bmBase, bn, upIdx = 0;
    if (MODE == 0) { bmBase = blockIdx.x * BMN; bn = blockIdx.y * BMN; }
    else {
        const int tilesPerUp = F_DIM / (BMN * 2);   // 32
        upIdx = blockIdx.y / tilesPerUp;
        bmBase = (blockIdx.y % tilesPerUp) * (BMN * 2);
        bn = blockIdx.x * BMN;
    }
    const int NTT = (MODE == 1) ? 2 : 1;

    const int w  = tid >> 6;
    const int l  = tid & 63;
    const int wr = (w >> 1) * 64;   // wave row origin
    const int wc = (w & 1) * 64;    // wave col origin

    // Staging map: 2048 chunks of 16B per K-tile, 8/thread (c = tid+256j).
    // chunk c: matrix p=c>>10 (0=A,1=B), row r=(c>>3)&127, phys slot sp=c&7.
    // logical slot = sp ^ (r&7) (XOR-8, involution). LDS dest linear.
    int srow[8], soff[8], sisB[8];
    #pragma unroll
    for (int j = 0; j < 8; ++j) {
        const int c = tid + 256 * j;
        const int q = c & 1023;
        const int r = q >> 3;
        sisB[j] = c >> 10;
        srow[j] = r;
        soff[j] = ((q & 7) ^ (r & 7)) * 16;
    }

    const char* gsrc[8];
    // set gsrc to segment start for row-tile bmc; return segment step count
    auto computePtrs = [&](int seg, int bmc) -> int {
        const f16 *Ab, *Bb; int str, st;
        switch (seg) {
            case 0:  Ab = d.a0; Bb = d.b0; str = d.str0; st = d.steps0; break;
            case 1:  Ab = d.a1; Bb = d.b1; str = d.str1; st = d.steps1; break;
            case 2:  Ab = d.a2; Bb = d.b2; str = d.str2; st = d.steps2; break;
            default: Ab = d.a3; Bb = d.b3; str = d.str3; st = d.steps3; break;
        }
        if (MODE == 1) Bb += (size_t)upIdx * F_DIM * 2 * D_DIM;
        #pragma unroll
        for (int j = 0; j < 8; ++j) {
            const f16* base = sisB[j] ? Bb : Ab;
            const int row0 = sisB[j] ? bn : bmc;
            gsrc[j] = (const char*)base
                    + (size_t)(row0 + srow[j]) * (size_t)str + soff[j];
        }
        return st;
    };

    #define STAGE(BUFSEL)                                                     \
        _Pragma("unroll")                                                     \
        for (int j = 0; j < 8; ++j) {                                         \
            __builtin_amdgcn_global_load_lds(                                 \
                (const __attribute__((address_space(1))) void*)gsrc[j],       \
                (__attribute__((address_space(3))) void*)                     \
                    (lds + (BUFSEL) * BUFB + (tid + 256 * j) * 16),           \
                16, 0, 0);                                                    \
            gsrc[j] += 128;   /* next 32-k packed block */                    \
        }

    const int fr = l & 15;
    const int ks = l >> 4;          // k-slot 0..3

    // Hoisted loop-invariant LDS read byte-offsets (XOR-8 swizzle math once)
    int offAH[4], offBH[4], offAL[4], offBL[4];
    #pragma unroll
    for (int f = 0; f < 4; ++f) {
        const int ra = wr + f * 16 + fr;
        const int rb = wc + f * 16 + fr;
        offAH[f] = ra * 128 + ((ks ^ (ra & 7)) * 16);
        offAL[f] = ra * 128 + (((4 + ks) ^ (ra & 7)) * 16);
        offBH[f] = PLNB + rb * 128 + ((ks ^ (rb & 7)) * 16);
        offBL[f] = PLNB + rb * 128 + (((4 + ks) ^ (rb & 7)) * 16);
    }

    const float MS = 4.8828125e-4f;   // 1/2048
    const int flag = (MODE == 1) ? *flagp : 0;

    for (int nt = 0; nt < NTT; ++nt) {
        const int bm = bmBase + nt * BMN;

        f32x4 accH[4][4], accM[4][4];
        const f32x4 zero = {0.f, 0.f, 0.f, 0.f};
        #pragma unroll
        for (int a = 0; a < 4; ++a)
            #pragma unroll
            for (int b = 0; b < 4; ++b) { accH[a][b] = zero; accM[a][b] = zero; }

        if (nt > 0) __syncthreads();   // epilogue LDS reads done before restage
        int seg = 0;
        int rem = computePtrs(0, bm);
        STAGE(0); --rem;                 // step 0 staged
        int cur = 0;
        for (int s = 0; s < d.totalSteps; ++s) {
            // buf[cur]'s loads issued one full step ago (hidden under MFMAs)
            asm volatile("s_waitcnt vmcnt(0)" ::: "memory");
            __syncthreads();

            const char* Lb = lds + cur * BUFB;
            // ---- read h-fragments (8 reads) ----
            f16x8 ah[4], bh[4];
            #pragma unroll
            for (int mf = 0; mf < 4; ++mf) ah[mf] = *(const f16x8*)(Lb + offAH[mf]);
            #pragma unroll
            for (int nf = 0; nf < 4; ++nf) bh[nf] = *(const f16x8*)(Lb + offBH[nf]);

            // ---- stage next step (segment boundary: recompute pointers) ----
            if (s + 1 < d.totalSteps) {
                if (rem == 0) { ++seg; rem = computePtrs(seg, bm); }
                STAGE(cur ^ 1); --rem;
            }

            // ---- read l-fragments (8 reads; overlap H-MFMAs) ----
            f16x8 al[4], bl[4];
            #pragma unroll
            for (int nf = 0; nf < 4; ++nf) bl[nf] = *(const f16x8*)(Lb + offBL[nf]);
            #pragma unroll
            for (int mf = 0; mf < 4; ++mf) al[mf] = *(const f16x8*)(Lb + offAL[mf]);

            // ---- H phase: 16 MFMAs ----
            __builtin_amdgcn_s_setprio(1);
            #pragma unroll
            for (int nf = 0; nf < 4; ++nf)
                #pragma unroll
                for (int mf = 0; mf < 4; ++mf)
                    accH[mf][nf] = __builtin_amdgcn_mfma_f32_16x16x32_f16(
                        ah[mf], bh[nf], accH[mf][nf], 0, 0, 0);
            __builtin_amdgcn_s_setprio(0);

            // ---- M phase: 32 MFMAs ----
            __builtin_amdgcn_s_setprio(1);
            #pragma unroll
            for (int nf = 0; nf < 4; ++nf)
                #pragma unroll
                for (int mf = 0; mf < 4; ++mf)
                    accM[mf][nf] = __builtin_amdgcn_mfma_f32_16x16x32_f16(
                        ah[mf], bl[nf], accM[mf][nf], 0, 0, 0);
            #pragma unroll
            for (int mf = 0; mf < 4; ++mf)
                #pragma unroll
                for (int nf = 0; nf < 4; ++nf)
                    accM[mf][nf] = __builtin_amdgcn_mfma_f32_16x16x32_f16(
                        al[mf], bh[nf], accM[mf][nf], 0, 0, 0);
            __builtin_amdgcn_s_setprio(0);

            cur ^= 1;
        }

        if (MODE == 0) {
            #pragma unroll
            for (int mf = 0; mf < 4; ++mf) {
                const int row0 = wr + mf * 16 + (l >> 4) * 4;
                #pragma unroll
                for (int nf = 0; nf < 4; ++nf) {
                    const int col = wc + nf * 16 + (l & 15);
                    const float bb = bias[bn + col];
                    #pragma unroll
                    for (int rr = 0; rr < 4; ++rr) {
                        const float v = accH[mf][nf][rr] + accM[mf][nf][rr] * MS;
                        C[(size_t)(bm + row0 + rr) * ldc + (bn + col)] = v + bb;
                    }
                }
            }
        } else {
            // ---- LDS-staged packed epilogue ----
            __syncthreads();   // all waves done reading K-loop LDS
            f16* Vq = Vp + (size_t)upIdx * F_DIM * (2 * F_DIM);

            #pragma unroll
            for (int mf = 0; mf < 4; ++mf) {
                const int row0 = wr + mf * 16 + (l >> 4) * 4;   // local fd row
                #pragma unroll
                for (int nf = 0; nf < 4; ++nf) {
                    const int col = wc + nf * 16 + (l & 15);    // local fu col
                    const size_t fu = (size_t)(bn + col);
                    const size_t fd0 = (size_t)(bm + row0);
                    float v[4];
                    #pragma unroll
                    for (int rr = 0; rr < 4; ++rr)
                        v[rr] = accH[mf][nf][rr] + accM[mf][nf][rr] * MS;

                    int m[4];
                    if (flag == 1) {
                        const int4 mm = *(const int4*)((const int*)conn +
                            (size_t)upIdx * F_DIM * F_DIM + fu * F_DIM + fd0);
                        m[0] = mm.x; m[1] = mm.y; m[2] = mm.z; m[3] = mm.w;
                    } else if (flag == 0) {
                        const uchar4 mm = *(const uchar4*)(conn +
                            (size_t)upIdx * F_DIM * F_DIM + fu * F_DIM + fd0);
                        m[0] = mm.x; m[1] = mm.y; m[2] = mm.z; m[3] = mm.w;
                    } else if (flag == 2) {
                        const long long* pp = (const long long*)conn +
                            (size_t)upIdx * F_DIM * F_DIM + fu * F_DIM + fd0;
                        m[0] = (int)pp[0]; m[1] = (int)pp[1];
                        m[2] = (int)pp[2]; m[3] = (int)pp[3];
                    } else {
                        const float4 mm = *(const float4*)((const float*)conn +
                            (size_t)upIdx * F_DIM * F_DIM + fu * F_DIM + fd0);
                        m[0] = mm.x != 0.f; m[1] = mm.y != 0.f;
                        m[2] = mm.z != 0.f; m[3] = mm.w != 0.f;
                    }
                    const int kloc = ((col >> 5) * 64 + (col & 31)) * 2;  // bytes
                    #pragma unroll
                    for (int rr = 0; rr < 4; ++rr) {
                        const float vv = m[rr] ? v[rr] : 0.f;
                        f16 hh, ll;
                        split_f32(vv, hh, ll);
                        char* rowp = lds + (row0 + rr) * EPSTRIDE;
                        *(f16*)(rowp + kloc)      = hh;
                        *(f16*)(rowp + kloc + 64) = ll;
                    }
                }
            }
            __syncthreads();

            // coalesced copy-out: 4096 chunks of 16B; 16 per thread
            const size_t rowBytes = (size_t)2 * F_DIM * 2;   // 32KB per fd row
            #pragma unroll
            for (int j = 0; j < 16; ++j) {
                const int c = tid + 256 * j;
                const int row = c >> 5;              // 0..127
                const int off = (c & 31) * 16;       // 0..496
                const f16x8 val = *(const f16x8*)(lds + row * EPSTRIDE + off);
                *(f16x8*)((char*)Vq + (size_t)(bm + row) * rowBytes
                          + (size_t)bn * 4 + off) = val;
            }
        }
    }
    #undef STAGE
}

// elementwise split into packed layout: row r of K -> 2K f16, blocks of
// [32 h | 32 l]. 8 contiguous k per thread (stay within one 32-block).
__global__ __launch_bounds__(256)
void split_kernel(const float* __restrict__ src, f16* __restrict__ dst,
                  size_t n, int K)
{
    const size_t e = ((size_t)blockIdx.x * 256 + threadIdx.x) * 8;
    if (e >= n) return;
    const size_t r = e / (size_t)K;
    const int k = (int)(e - r * (size_t)K);
    const float4 a = *(const float4*)(src + e);
    const float4 b = *(const float4*)(src + e + 4);
    f16 hv[8], lv[8];
    const float s[8] = {a.x, a.y, a.z, a.w, b.x, b.y, b.z, b.w};
    #pragma unroll
    for (int i = 0; i < 8; ++i) split_f32(s[i], hv[i], lv[i]);
    const size_t base = r * (size_t)(2 * K) + (size_t)((k >> 5) * 64 + (k & 31));
    *(f16x8*)(dst + base)      = *(const f16x8*)hv;
    *(f16x8*)(dst + base + 32) = *(const f16x8*)lv;
}

// W_enc [768][8192] -> packed W_encT rows f (K=768); reads coalesced along f
__global__ __launch_bounds__(256)
void transpose_split_kernel(const float* __restrict__ W, f16* __restrict__ dst)
{
    const int f = blockIdx.x * 256 + threadIdx.x;
    for (int dc = 0; dc < D_DIM / 8; ++dc) {
        const int k = dc * 8;
        f16 hv[8], lv[8];
        #pragma unroll
        for (int j = 0; j < 8; ++j)
            split_f32(W[(size_t)(k + j) * F_DIM + f], hv[j], lv[j]);
        const size_t base = (size_t)f * (2 * D_DIM) + (k >> 5) * 64 + (k & 31);
        *(f16x8*)(dst + base)      = *(const f16x8*)hv;
        *(f16x8*)(dst + base + 32) = *(const f16x8*)lv;
    }
}

// conn_mask storage-layout detection: 0=u8, 1=i32, 2=i64, 3=f32
__global__ void detect_kernel(const int* __restrict__ conn, int* __restrict__ flag)
{
    __shared__ int not01, notf01, odd_nz;
    if (threadIdx.x == 0) { not01 = 0; notf01 = 0; odd_nz = 0; }
    __syncthreads();
    const int4 v = ((const int4*)conn)[threadIdx.x];
    const unsigned a[4] = {(unsigned)v.x, (unsigned)v.y,
                           (unsigned)v.z, (unsigned)v.w};
    int l_not01 = 0, l_notf = 0;
    #pragma unroll
    for (int i = 0; i < 4; ++i) {
        if (a[i] > 1u) l_not01 = 1;
        if (a[i] != 0u && a[i] != 0x3F800000u) l_notf = 1;
    }
    if (l_not01) atomicOr(&not01, 1);
    if (l_notf)  atomicOr(&notf01, 1);
    if (a[1] | a[3]) atomicOr(&odd_nz, 1);
    __syncthreads();
    if (threadIdx.x == 0) {
        int f;
        if (!not01)        f = odd_nz ? 1 : 2;
        else if (!notf01)  f = 3;
        else               f = 0;
        *flag = f;
    }
}

__global__ void bias2_kernel(const float* __restrict__ W_enc,
                             const float* __restrict__ b_enc,
                             const float* __restrict__ up_b_dec,
                             int nup, float* __restrict__ bias2)
{
    const int g = blockIdx.x * 256 + threadIdx.x;
    if (g >= F_DIM) return;
    float s = b_enc[g];
    for (int d = 0; d < D_DIM; ++d) {
        float ub = 0.f;
        for (int i = 0; i < nup; ++i) ub += up_b_dec[i * D_DIM + d];
        s = __builtin_fmaf(ub, W_enc[(size_t)d * F_DIM + g], s);
    }
    bias2[g] = s;
}

// exact radix top-k (ties -> lowest index), relu, sparse decode. 512 thr.
__global__ __launch_bounds__(512)
void topk_decode_kernel(const float* __restrict__ approx,
                        const float* __restrict__ W_dec,
                        const float* __restrict__ b_dec,
                        const int* __restrict__ kptr,
                        float* __restrict__ out)
{
    __shared__ unsigned keys[F_DIM];
    __shared__ int hist[256];
    __shared__ unsigned sh_prefix;
    __shared__ int sh_need;
    __shared__ int sel_cnt, eq_cnt;
    __shared__ int sidx[128];
    __shared__ float sval[128];
    __shared__ int eqidx[1024];

    const int tid = threadIdx.x;
    const int row = blockIdx.x;
    const int k = *kptr;
    const float* arow = approx + (size_t)row * F_DIM;

    for (int j = tid; j < F_DIM; j += 512) {
        unsigned u = __float_as_uint(arow[j]);
        u = (u & 0x80000000u) ? ~u : (u | 0x80000000u);
        keys[j] = u;
    }
    if (tid == 0) { sh_prefix = 0u; sh_need = k; sel_cnt = 0; eq_cnt = 0; }
    __syncthreads();

    for (int shift = 24; shift >= 0; shift -= 8) {
        if (tid < 256) hist[tid] = 0;
        __syncthreads();
        const unsigned pfx = sh_prefix;
        for (int j = tid; j < F_DIM; j += 512) {
            const unsigned u = keys[j];
            const bool match =
                (shift == 24) || ((u >> (shift + 8)) == (pfx >> (shift + 8)));
            if (match) atomicAdd(&hist[(u >> shift) & 255], 1);
        }
        __syncthreads();
        if (tid == 0) {
            int need = sh_need;
            for (int b = 255; b >= 0; --b) {
                const int c = hist[b];
                if (c >= need) {
                    sh_prefix = pfx | ((unsigned)b << shift);
                    sh_need = need;
                    break;
                }
                need -= c;
            }
        }
        __syncthreads();
    }
    const unsigned T = sh_prefix;
    const int r = sh_need;

    for (int j = tid; j < F_DIM; j += 512) {
        const unsigned u = keys[j];
        if (u > T) {
            const int p = atomicAdd(&sel_cnt, 1);
            sidx[p] = j;
        } else if (u == T) {
            const int p = atomicAdd(&eq_cnt, 1);
            if (p < 1024) eqidx[p] = j;
        }
    }
    __syncthreads();

    if (tid == 0) {
        const int m = sel_cnt;
        const int e = eq_cnt < 1024 ? eq_cnt : 1024;
        for (int t2 = 0; t2 < r; ++t2) {
            int best = 0x7FFFFFFF, bi = -1;
            for (int q = 0; q < e; ++q) {
                const int v = eqidx[q];
                if (v >= 0 && v < best) { best = v; bi = q; }
            }
            if (bi >= 0) { eqidx[bi] = -1; sidx[m + t2] = best; }
        }
        sel_cnt = m + r;
        const int n = sel_cnt;
        for (int a2 = 1; a2 < n; ++a2) {
            const int v = sidx[a2];
            int b2 = a2 - 1;
            while (b2 >= 0 && sidx[b2] > v) { sidx[b2 + 1] = sidx[b2]; --b2; }
            sidx[b2 + 1] = v;
        }
    }
    __syncthreads();

    const int total = sel_cnt;
    for (int j = tid; j < total; j += 512) {
        const float v = arow[sidx[j]];
        sval[j] = v > 0.f ? v : 0.f;
    }
    __syncthreads();

    // decode: 512 threads cover D=768 as tid (all) + tid+512 (first 256)
    float acc0 = b_dec[tid];
    float acc1 = (tid < 256) ? b_dec[tid + 512] : 0.f;
    for (int j = 0; j < total; ++j) {
        const float v = sval[j];
        const float* wv = W_dec + (size_t)sidx[j] * D_DIM;
        acc0 = __builtin_fmaf(v, wv[tid], acc0);
        if (tid < 256) acc1 = __builtin_fmaf(v, wv[tid + 512], acc1);
    }
    float* orow = out + (size_t)row * D_DIM;
    orow[tid] = acc0;
    if (tid < 256) orow[tid + 512] = acc1;
}

extern "C" void kernel_launch(void* const* d_in, const int* in_sizes, int n_in,
                              void* d_out, int out_size, void* d_ws, size_t ws_size,
                              hipStream_t stream)
{
    const float* x         = (const float*)d_in[1];
    const float* up_feats  = (const float*)d_in[2];
    const float* W_enc     = (const float*)d_in[3];
    const float* b_enc     = (const float*)d_in[4];
    const float* W_dec     = (const float*)d_in[5];
    const float* b_dec     = (const float*)d_in[6];
    const float* up_W_dec  = (const float*)d_in[7];
    const float* up_b_dec  = (const float*)d_in[8];
    const unsigned char* conn = (const unsigned char*)d_in[9];
    const int* kptr        = (const int*)d_in[10];

    const int BS  = in_sizes[1] / D_DIM;    // 2048
    const int NUP = in_sizes[8] / D_DIM;    // 3

    char* ws = (char*)d_ws;
    size_t off = 0;
    auto alloc = [&](size_t bytes) -> char* {
        off = (off + 255) & ~(size_t)255;
        char* p = ws + off; off += bytes; return p;
    };
    float* approx = (float*)alloc((size_t)BS * F_DIM * 4);
    float* bias2  = (float*)alloc(F_DIM * 4);
    int*   flag   = (int*)alloc(256);
    // packed arrays: logical n elems -> 2n f16 = 4n bytes
    f16* xp   = (f16*)alloc((size_t)BS * D_DIM * 4);
    f16* Wtp  = (f16*)alloc((size_t)F_DIM * D_DIM * 4);
    f16* uwdp = (f16*)alloc((size_t)NUP * F_DIM * D_DIM * 4);
    f16* ufp  = (f16*)alloc((size_t)NUP * BS * F_DIM * 4);
    f16* vp   = (f16*)alloc((size_t)NUP * F_DIM * F_DIM * 4);  // 805MB, fits

    detect_kernel<<<1, 256, 0, stream>>>((const int*)conn, flag);
    bias2_kernel<<<F_DIM / 256, 256, 0, stream>>>(W_enc, b_enc, up_b_dec, NUP, bias2);

    split_kernel<<<(unsigned)((size_t)BS * D_DIM / 2048), 256, 0, stream>>>(
        x, xp, (size_t)BS * D_DIM, D_DIM);
    split_kernel<<<(unsigned)((size_t)NUP * F_DIM * D_DIM / 2048), 256, 0, stream>>>(
        up_W_dec, uwdp, (size_t)NUP * F_DIM * D_DIM, D_DIM);
    split_kernel<<<(unsigned)((size_t)NUP * BS * F_DIM / 2048), 256, 0, stream>>>(
        up_feats, ufp, (size_t)NUP * BS * F_DIM, F_DIM);
    transpose_split_kernel<<<F_DIM / 256, 256, 0, stream>>>(W_enc, Wtp);

    // G1 merged: all upstream virt panels, NT=2 fd-tiles per block
    {
        SegDesc d1{};
        d1.a0 = Wtp; d1.b0 = uwdp;
        d1.str0 = D_DIM * 4; d1.steps0 = D_DIM / 32;
        d1.totalSteps = D_DIM / 32;
        mfma_gemm<1><<<dim3(F_DIM / BMN, (F_DIM / (BMN * 2)) * NUP), 256, 0,
                       stream>>>(d1, nullptr, 0, vp, nullptr, conn, flag);
    }

    // G2 merged: approx = [x | uf_i...] @ [W_encT ; v_i...]^T + bias2
    {
        SegDesc d2{};
        d2.a0 = xp;  d2.b0 = Wtp;
        d2.str0 = D_DIM * 4; d2.steps0 = D_DIM / 32;
        int total = D_DIM / 32;
        const f16* aseg[3]; const f16* bseg[3];
        for (int i = 0; i < NUP && i < 3; ++i) {
            aseg[i] = ufp + (size_t)i * BS * 2 * F_DIM;
            bseg[i] = vp  + (size_t)i * F_DIM * 2 * F_DIM;
            total += F_DIM / 32;
        }
        if (NUP >= 1) { d2.a1 = aseg[0]; d2.b1 = bseg[0];
                        d2.str1 = F_DIM * 4; d2.steps1 = F_DIM / 32; }
        if (NUP >= 2) { d2.a2 = aseg[1]; d2.b2 = bseg[1];
                        d2.str2 = F_DIM * 4; d2.steps2 = F_DIM / 32; }
        if (NUP >= 3) { d2.a3 = aseg[2]; d2.b3 = bseg[2];
                        d2.str3 = F_DIM * 4; d2.steps3 = F_DIM / 32; }
        d2.totalSteps = total;
        mfma_gemm<0><<<dim3(BS / BMN, F_DIM / BMN), 256, 0, stream>>>(
            d2, approx, F_DIM, nullptr, bias2, nullptr, flag);
    }

    topk_decode_kernel<<<BS, 512, 0, stream>>>(
        approx, W_dec, b_dec, kptr, (float*)d_out);
}

// Round 18
// 3515.381 us; speedup vs baseline: 1.0828x; 1.0828x over previous
//
#include <hip/hip_runtime.h>
#include <hip/hip_bf16.h>

// SCAE forward on MI355X — f16 split-MFMA (Ootomo 3-product) pipeline.
//   v = h + l/2048 (f16 h,l; subnormal-guarded)  =>
//   A@B = Ah@Bh + (Ah@Bl + Al@Bh)/2048   (drop 2^-22 term)
// R18 = R16 exact revert (best 3568us; R17's NT=2 G1 + 512-thr topk both
// regressed: intra-block phase serialization loses to inter-block overlap)
// + transpose_split parallelized 32 -> 256 blocks (was a 12.5%-occupancy
// latency tail of ~90us before G1 could start).
// Then exact radix top-k (ties->lowest index), relu, sparse decode.

#define D_DIM 768
#define F_DIM 8192

typedef _Float16 f16;
typedef _Float16 f16x8 __attribute__((ext_vector_type(8)));
typedef float f32x4 __attribute__((ext_vector_type(4)));

#define BMN 128
#define BUFB 32768    // one K-tile: A 16KB + B 16KB (128 rows x 128B each)
#define PLNB 16384    // B region offset ([h|l] packed rows, XOR-8 swizzled)
#define EPSTRIDE 528  // epilogue LDS row stride (512B data + 16B pad)
#define LDSBYTES 69632

struct SegDesc {
    const f16 *a0, *a1, *a2, *a3;
    const f16 *b0, *b1, *b2, *b3;
    int str0, str1, str2, str3;       // A/B row stride in BYTES (= K*4)
    int steps0, steps1, steps2, steps3;
    int totalSteps;
};

__device__ inline void split_f32(float v, f16& h, f16& l) {
    float hf = (float)(f16)v;
    if (__builtin_fabsf(hf) < 6.1035156e-5f) hf = 0.f;   // keep h MFMA-normal
    h = (f16)hf;
    l = (f16)((v - hf) * 2048.0f);
}

// MODE 0: C = comb + bias[col]  (final approx; grid x=bm, y=bn)
// MODE 1: Vp = packed_split(comb * mask)  (all upstreams; upIdx = by>>6)
template<int MODE>
__global__ __launch_bounds__(256, 2)
void mfma_gemm(SegDesc d, float* __restrict__ C, int ldc,
               f16* __restrict__ Vp,
               const float* __restrict__ bias,
               const unsigned char* __restrict__ conn,
               const int* __restrict__ flagp)
{
    __shared__ char lds[LDSBYTES];   // K-loop: 2x32KB dbuf; epilogue: tile
    const int tid = threadIdx.x;
    int bm, bn, upIdx = 0;
    if (MODE == 0) { bm = blockIdx.x * BMN; bn = blockIdx.y * BMN; }
    else { upIdx = blockIdx.y >> 6; bm = (blockIdx.y & 63) * BMN;
           bn = blockIdx.x * BMN; }

    const int w  = tid >> 6;
    const int l  = tid & 63;
    const int wr = (w >> 1) * 64;   // wave row origin
    const int wc = (w & 1) * 64;    // wave col origin

    // Staging map: 2048 chunks of 16B per K-tile, 8/thread (c = tid+256j).
    // chunk c: matrix p=c>>10 (0=A,1=B), row r=(c>>3)&127, phys slot sp=c&7.
    // logical slot = sp ^ (r&7) (XOR-8, involution). LDS dest linear.
    int srow[8], soff[8], sisB[8];
    #pragma unroll
    for (int j = 0; j < 8; ++j) {
        const int c = tid + 256 * j;
        const int q = c & 1023;
        const int r = q >> 3;
        sisB[j] = c >> 10;
        srow[j] = r;
        soff[j] = ((q & 7) ^ (r & 7)) * 16;
    }

    const char* gsrc[8];
    // set gsrc to segment start; return the segment's step count
    auto computePtrs = [&](int seg) -> int {
        const f16 *Ab, *Bb; int str, st;
        switch (seg) {
            case 0:  Ab = d.a0; Bb = d.b0; str = d.str0; st = d.steps0; break;
            case 1:  Ab = d.a1; Bb = d.b1; str = d.str1; st = d.steps1; break;
            case 2:  Ab = d.a2; Bb = d.b2; str = d.str2; st = d.steps2; break;
            default: Ab = d.a3; Bb = d.b3; str = d.str3; st = d.steps3; break;
        }
        if (MODE == 1) Bb += (size_t)upIdx * F_DIM * 2 * D_DIM;
        #pragma unroll
        for (int j = 0; j < 8; ++j) {
            const f16* base = sisB[j] ? Bb : Ab;
            const int row0 = sisB[j] ? bn : bm;
            gsrc[j] = (const char*)base
                    + (size_t)(row0 + srow[j]) * (size_t)str + soff[j];
        }
        return st;
    };

    #define STAGE(BUFSEL)                                                     \
        _Pragma("unroll")                                                     \
        for (int j = 0; j < 8; ++j) {                                         \
            __builtin_amdgcn_global_load_lds(                                 \
                (const __attribute__((address_space(1))) void*)gsrc[j],       \
                (__attribute__((address_space(3))) void*)                     \
                    (lds + (BUFSEL) * BUFB + (tid + 256 * j) * 16),           \
                16, 0, 0);                                                    \
            gsrc[j] += 128;   /* next 32-k packed block */                    \
        }

    f32x4 accH[4][4], accM[4][4];
    const f32x4 zero = {0.f, 0.f, 0.f, 0.f};
    #pragma unroll
    for (int a = 0; a < 4; ++a)
        #pragma unroll
        for (int b = 0; b < 4; ++b) { accH[a][b] = zero; accM[a][b] = zero; }

    const int fr = l & 15;
    const int ks = l >> 4;          // k-slot 0..3

    // Hoisted loop-invariant LDS read byte-offsets (XOR-8 swizzle math once)
    int offAH[4], offBH[4], offAL[4], offBL[4];
    #pragma unroll
    for (int f = 0; f < 4; ++f) {
        const int ra = wr + f * 16 + fr;
        const int rb = wc + f * 16 + fr;
        offAH[f] = ra * 128 + ((ks ^ (ra & 7)) * 16);
        offAL[f] = ra * 128 + (((4 + ks) ^ (ra & 7)) * 16);
        offBH[f] = PLNB + rb * 128 + ((ks ^ (rb & 7)) * 16);
        offBL[f] = PLNB + rb * 128 + (((4 + ks) ^ (rb & 7)) * 16);
    }

    int seg = 0;
    int rem = computePtrs(0);
    STAGE(0); --rem;                 // step 0 staged
    int cur = 0;
    for (int s = 0; s < d.totalSteps; ++s) {
        // buf[cur]'s loads were issued one full step ago (hidden under MFMAs)
        asm volatile("s_waitcnt vmcnt(0)" ::: "memory");
        __syncthreads();

        const char* Lb = lds + cur * BUFB;
        // ---- read h-fragments (8 reads) ----
        f16x8 ah[4], bh[4];
        #pragma unroll
        for (int mf = 0; mf < 4; ++mf) ah[mf] = *(const f16x8*)(Lb + offAH[mf]);
        #pragma unroll
        for (int nf = 0; nf < 4; ++nf) bh[nf] = *(const f16x8*)(Lb + offBH[nf]);

        // ---- stage next step (segment boundary: recompute pointers) ----
        if (s + 1 < d.totalSteps) {
            if (rem == 0) { ++seg; rem = computePtrs(seg); }
            STAGE(cur ^ 1); --rem;
        }

        // ---- read l-fragments (8 reads; overlap H-MFMAs via lgkmcnt) ----
        f16x8 al[4], bl[4];
        #pragma unroll
        for (int nf = 0; nf < 4; ++nf) bl[nf] = *(const f16x8*)(Lb + offBL[nf]);
        #pragma unroll
        for (int mf = 0; mf < 4; ++mf) al[mf] = *(const f16x8*)(Lb + offAL[mf]);

        // ---- H phase: 16 MFMAs ----
        __builtin_amdgcn_s_setprio(1);
        #pragma unroll
        for (int nf = 0; nf < 4; ++nf)
            #pragma unroll
            for (int mf = 0; mf < 4; ++mf)
                accH[mf][nf] = __builtin_amdgcn_mfma_f32_16x16x32_f16(
                    ah[mf], bh[nf], accH[mf][nf], 0, 0, 0);
        __builtin_amdgcn_s_setprio(0);

        // ---- M phase: 32 MFMAs ----
        __builtin_amdgcn_s_setprio(1);
        #pragma unroll
        for (int nf = 0; nf < 4; ++nf)
            #pragma unroll
            for (int mf = 0; mf < 4; ++mf)
                accM[mf][nf] = __builtin_amdgcn_mfma_f32_16x16x32_f16(
                    ah[mf], bl[nf], accM[mf][nf], 0, 0, 0);
        #pragma unroll
        for (int mf = 0; mf < 4; ++mf)
            #pragma unroll
            for (int nf = 0; nf < 4; ++nf)
                accM[mf][nf] = __builtin_amdgcn_mfma_f32_16x16x32_f16(
                    al[mf], bh[nf], accM[mf][nf], 0, 0, 0);
        __builtin_amdgcn_s_setprio(0);

        cur ^= 1;
    }
    #undef STAGE

    const float MS = 4.8828125e-4f;   // 1/2048
    const int flag = (MODE == 1) ? *flagp : 0;

    if (MODE == 0) {
        #pragma unroll
        for (int mf = 0; mf < 4; ++mf) {
            const int row0 = wr + mf * 16 + (l >> 4) * 4;
            #pragma unroll
            for (int nf = 0; nf < 4; ++nf) {
                const int col = wc + nf * 16 + (l & 15);
                const float bb = bias[bn + col];
                #pragma unroll
                for (int rr = 0; rr < 4; ++rr) {
                    const float v = accH[mf][nf][rr] + accM[mf][nf][rr] * MS;
                    C[(size_t)(bm + row0 + rr) * ldc + (bn + col)] = v + bb;
                }
            }
        }
    } else {
        // ---- LDS-staged packed epilogue ----
        __syncthreads();   // all waves done reading K-loop LDS
        f16* Vq = Vp + (size_t)upIdx * F_DIM * (2 * F_DIM);

        #pragma unroll
        for (int mf = 0; mf < 4; ++mf) {
            const int row0 = wr + mf * 16 + (l >> 4) * 4;   // local fd row
            #pragma unroll
            for (int nf = 0; nf < 4; ++nf) {
                const int col = wc + nf * 16 + (l & 15);    // local fu col
                const size_t fu = (size_t)(bn + col);
                const size_t fd0 = (size_t)(bm + row0);
                float v[4];
                #pragma unroll
                for (int rr = 0; rr < 4; ++rr)
                    v[rr] = accH[mf][nf][rr] + accM[mf][nf][rr] * MS;

                int m[4];
                if (flag == 1) {
                    const int4 mm = *(const int4*)((const int*)conn +
                        (size_t)upIdx * F_DIM * F_DIM + fu * F_DIM + fd0);
                    m[0] = mm.x; m[1] = mm.y; m[2] = mm.z; m[3] = mm.w;
                } else if (flag == 0) {
                    const uchar4 mm = *(const uchar4*)(conn +
                        (size_t)upIdx * F_DIM * F_DIM + fu * F_DIM + fd0);
                    m[0] = mm.x; m[1] = mm.y; m[2] = mm.z; m[3] = mm.w;
                } else if (flag == 2) {
                    const long long* pp = (const long long*)conn +
                        (size_t)upIdx * F_DIM * F_DIM + fu * F_DIM + fd0;
                    m[0] = (int)pp[0]; m[1] = (int)pp[1];
                    m[2] = (int)pp[2]; m[3] = (int)pp[3];
                } else {
                    const float4 mm = *(const float4*)((const float*)conn +
                        (size_t)upIdx * F_DIM * F_DIM + fu * F_DIM + fd0);
                    m[0] = mm.x != 0.f; m[1] = mm.y != 0.f;
                    m[2] = mm.z != 0.f; m[3] = mm.w != 0.f;
                }
                // packed-local f16 index within row: (col>>5)*64 + (col&31)
                const int kloc = ((col >> 5) * 64 + (col & 31)) * 2;  // bytes
                #pragma unroll
                for (int rr = 0; rr < 4; ++rr) {
                    const float vv = m[rr] ? v[rr] : 0.f;
                    f16 hh, ll;
                    split_f32(vv, hh, ll);
                    char* rowp = lds + (row0 + rr) * EPSTRIDE;
                    *(f16*)(rowp + kloc)      = hh;
                    *(f16*)(rowp + kloc + 64) = ll;
                }
            }
        }
        __syncthreads();

        // coalesced copy-out: 4096 chunks of 16B; 16 per thread
        const size_t rowBytes = (size_t)2 * F_DIM * 2;   // 32768 B per fd row
        #pragma unroll
        for (int j = 0; j < 16; ++j) {
            const int c = tid + 256 * j;
            const int row = c >> 5;              // 0..127
            const int off = (c & 31) * 16;       // 0..496
            const f16x8 val = *(const f16x8*)(lds + row * EPSTRIDE + off);
            *(f16x8*)((char*)Vq + (size_t)(bm + row) * rowBytes
                      + (size_t)bn * 4 + off) = val;
        }
    }
}

// elementwise split into packed layout: row r of K -> 2K f16, blocks of
// [32 h | 32 l]. 8 contiguous k per thread (stay within one 32-block).
__global__ __launch_bounds__(256)
void split_kernel(const float* __restrict__ src, f16* __restrict__ dst,
                  size_t n, int K)
{
    const size_t e = ((size_t)blockIdx.x * 256 + threadIdx.x) * 8;
    if (e >= n) return;
    const size_t r = e / (size_t)K;
    const int k = (int)(e - r * (size_t)K);
    const float4 a = *(const float4*)(src + e);
    const float4 b = *(const float4*)(src + e + 4);
    f16 hv[8], lv[8];
    const float s[8] = {a.x, a.y, a.z, a.w, b.x, b.y, b.z, b.w};
    #pragma unroll
    for (int i = 0; i < 8; ++i) split_f32(s[i], hv[i], lv[i]);
    const size_t base = r * (size_t)(2 * K) + (size_t)((k >> 5) * 64 + (k & 31));
    *(f16x8*)(dst + base)      = *(const f16x8*)hv;
    *(f16x8*)(dst + base + 32) = *(const f16x8*)lv;
}

// W_enc [768][8192] -> packed W_encT rows f (K=768); reads coalesced along f.
// 2D grid (32 x 8): blockIdx.y owns 12 of the 96 d-chunks (8x parallelism
// vs R16's 32-block latency tail).
__global__ __launch_bounds__(256)
void transpose_split_kernel(const float* __restrict__ W, f16* __restrict__ dst)
{
    const int f = blockIdx.x * 256 + threadIdx.x;
    const int dc0 = blockIdx.y * (D_DIM / 8 / 8);   // 12 chunks per y-block
    for (int dc = dc0; dc < dc0 + (D_DIM / 8 / 8); ++dc) {
        const int k = dc * 8;
        f16 hv[8], lv[8];
        #pragma unroll
        for (int j = 0; j < 8; ++j)
            split_f32(W[(size_t)(k + j) * F_DIM + f], hv[j], lv[j]);
        const size_t base = (size_t)f * (2 * D_DIM) + (k >> 5) * 64 + (k & 31);
        *(f16x8*)(dst + base)      = *(const f16x8*)hv;
        *(f16x8*)(dst + base + 32) = *(const f16x8*)lv;
    }
}

// conn_mask storage-layout detection: 0=u8, 1=i32, 2=i64, 3=f32
__global__ void detect_kernel(const int* __restrict__ conn, int* __restrict__ flag)
{
    __shared__ int not01, notf01, odd_nz;
    if (threadIdx.x == 0) { not01 = 0; notf01 = 0; odd_nz = 0; }
    __syncthreads();
    const int4 v = ((const int4*)conn)[threadIdx.x];
    const unsigned a[4] = {(unsigned)v.x, (unsigned)v.y,
                           (unsigned)v.z, (unsigned)v.w};
    int l_not01 = 0, l_notf = 0;
    #pragma unroll
    for (int i = 0; i < 4; ++i) {
        if (a[i] > 1u) l_not01 = 1;
        if (a[i] != 0u && a[i] != 0x3F800000u) l_notf = 1;
    }
    if (l_not01) atomicOr(&not01, 1);
    if (l_notf)  atomicOr(&notf01, 1);
    if (a[1] | a[3]) atomicOr(&odd_nz, 1);
    __syncthreads();
    if (threadIdx.x == 0) {
        int f;
        if (!not01)        f = odd_nz ? 1 : 2;
        else if (!notf01)  f = 3;
        else               f = 0;
        *flag = f;
    }
}

__global__ void bias2_kernel(const float* __restrict__ W_enc,
                             const float* __restrict__ b_enc,
                             const float* __restrict__ up_b_dec,
                             int nup, float* __restrict__ bias2)
{
    const int g = blockIdx.x * 256 + threadIdx.x;
    if (g >= F_DIM) return;
    float s = b_enc[g];
    for (int d = 0; d < D_DIM; ++d) {
        float ub = 0.f;
        for (int i = 0; i < nup; ++i) ub += up_b_dec[i * D_DIM + d];
        s = __builtin_fmaf(ub, W_enc[(size_t)d * F_DIM + g], s);
    }
    bias2[g] = s;
}

// exact radix top-k (ties -> lowest index), relu, sparse decode
__global__ __launch_bounds__(256)
void topk_decode_kernel(const float* __restrict__ approx,
                        const float* __restrict__ W_dec,
                        const float* __restrict__ b_dec,
                        const int* __restrict__ kptr,
                        float* __restrict__ out)
{
    __shared__ unsigned keys[F_DIM];
    __shared__ int hist[256];
    __shared__ unsigned sh_prefix;
    __shared__ int sh_need;
    __shared__ int sel_cnt, eq_cnt;
    __shared__ int sidx[128];
    __shared__ float sval[128];
    __shared__ int eqidx[1024];

    const int tid = threadIdx.x;
    const int row = blockIdx.x;
    const int k = *kptr;
    const float* arow = approx + (size_t)row * F_DIM;

    for (int j = tid; j < F_DIM; j += 256) {
        unsigned u = __float_as_uint(arow[j]);
        u = (u & 0x80000000u) ? ~u : (u | 0x80000000u);
        keys[j] = u;
    }
    if (tid == 0) { sh_prefix = 0u; sh_need = k; sel_cnt = 0; eq_cnt = 0; }
    __syncthreads();

    for (int shift = 24; shift >= 0; shift -= 8) {
        if (tid < 256) hist[tid] = 0;
        __syncthreads();
        const unsigned pfx = sh_prefix;
        for (int j = tid; j < F_DIM; j += 256) {
            const unsigned u = keys[j];
            const bool match =
                (shift == 24) || ((u >> (shift + 8)) == (pfx >> (shift + 8)));
            if (match) atomicAdd(&hist[(u >> shift) & 255], 1);
        }
        __syncthreads();
        if (tid == 0) {
            int need = sh_need;
            for (int b = 255; b >= 0; --b) {
                const int c = hist[b];
                if (c >= need) {
                    sh_prefix = pfx | ((unsigned)b << shift);
                    sh_need = need;
                    break;
                }
                need -= c;
            }
        }
        __syncthreads();
    }
    const unsigned T = sh_prefix;
    const int r = sh_need;

    for (int j = tid; j < F_DIM; j += 256) {
        const unsigned u = keys[j];
        if (u > T) {
            const int p = atomicAdd(&sel_cnt, 1);
            sidx[p] = j;
        } else if (u == T) {
            const int p = atomicAdd(&eq_cnt, 1);
            if (p < 1024) eqidx[p] = j;
        }
    }
    __syncthreads();

    if (tid == 0) {
        const int m = sel_cnt;
        const int e = eq_cnt < 1024 ? eq_cnt : 1024;
        for (int t2 = 0; t2 < r; ++t2) {
            int best = 0x7FFFFFFF, bi = -1;
            for (int q = 0; q < e; ++q) {
                const int v = eqidx[q];
                if (v >= 0 && v < best) { best = v; bi = q; }
            }
            if (bi >= 0) { eqidx[bi] = -1; sidx[m + t2] = best; }
        }
        sel_cnt = m + r;
        const int n = sel_cnt;
        for (int a2 = 1; a2 < n; ++a2) {
            const int v = sidx[a2];
            int b2 = a2 - 1;
            while (b2 >= 0 && sidx[b2] > v) { sidx[b2 + 1] = sidx[b2]; --b2; }
            sidx[b2 + 1] = v;
        }
    }
    __syncthreads();

    const int total = sel_cnt;
    for (int j = tid; j < total; j += 256) {
        const float v = arow[sidx[j]];
        sval[j] = v > 0.f ? v : 0.f;
    }
    __syncthreads();

    float acc0 = b_dec[tid];
    float acc1 = b_dec[tid + 256];
    float acc2 = b_dec[tid + 512];
    for (int j = 0; j < total; ++j) {
        const float v = sval[j];
        const float* wv = W_dec + (size_t)sidx[j] * D_DIM;
        acc0 = __builtin_fmaf(v, wv[tid],       acc0);
        acc1 = __builtin_fmaf(v, wv[tid + 256], acc1);
        acc2 = __builtin_fmaf(v, wv[tid + 512], acc2);
    }
    float* orow = out + (size_t)row * D_DIM;
    orow[tid] = acc0;
    orow[tid + 256] = acc1;
    orow[tid + 512] = acc2;
}

extern "C" void kernel_launch(void* const* d_in, const int* in_sizes, int n_in,
                              void* d_out, int out_size, void* d_ws, size_t ws_size,
                              hipStream_t stream)
{
    const float* x         = (const float*)d_in[1];
    const float* up_feats  = (const float*)d_in[2];
    const float* W_enc     = (const float*)d_in[3];
    const float* b_enc     = (const float*)d_in[4];
    const float* W_dec     = (const float*)d_in[5];
    const float* b_dec     = (const float*)d_in[6];
    const float* up_W_dec  = (const float*)d_in[7];
    const float* up_b_dec  = (const float*)d_in[8];
    const unsigned char* conn = (const unsigned char*)d_in[9];
    const int* kptr        = (const int*)d_in[10];

    const int BS  = in_sizes[1] / D_DIM;    // 2048
    const int NUP = in_sizes[8] / D_DIM;    // 3

    char* ws = (char*)d_ws;
    size_t off = 0;
    auto alloc = [&](size_t bytes) -> char* {
        off = (off + 255) & ~(size_t)255;
        char* p = ws + off; off += bytes; return p;
    };
    float* approx = (float*)alloc((size_t)BS * F_DIM * 4);
    float* bias2  = (float*)alloc(F_DIM * 4);
    int*   flag   = (int*)alloc(256);
    // packed arrays: logical n elems -> 2n f16 = 4n bytes
    f16* xp   = (f16*)alloc((size_t)BS * D_DIM * 4);
    f16* Wtp  = (f16*)alloc((size_t)F_DIM * D_DIM * 4);
    f16* uwdp = (f16*)alloc((size_t)NUP * F_DIM * D_DIM * 4);
    f16* ufp  = (f16*)alloc((size_t)NUP * BS * F_DIM * 4);
    f16* vp   = (f16*)alloc((size_t)NUP * F_DIM * F_DIM * 4);  // 805MB, fits

    detect_kernel<<<1, 256, 0, stream>>>((const int*)conn, flag);
    bias2_kernel<<<F_DIM / 256, 256, 0, stream>>>(W_enc, b_enc, up_b_dec, NUP, bias2);

    split_kernel<<<(unsigned)((size_t)BS * D_DIM / 2048), 256, 0, stream>>>(
        x, xp, (size_t)BS * D_DIM, D_DIM);
    split_kernel<<<(unsigned)((size_t)NUP * F_DIM * D_DIM / 2048), 256, 0, stream>>>(
        up_W_dec, uwdp, (size_t)NUP * F_DIM * D_DIM, D_DIM);
    split_kernel<<<(unsigned)((size_t)NUP * BS * F_DIM / 2048), 256, 0, stream>>>(
        up_feats, ufp, (size_t)NUP * BS * F_DIM, F_DIM);
    transpose_split_kernel<<<dim3(F_DIM / 256, 8), 256, 0, stream>>>(W_enc, Wtp);

    // G1 merged: all upstream virt panels in one dispatch
    {
        SegDesc d1{};
        d1.a0 = Wtp; d1.b0 = uwdp;
        d1.str0 = D_DIM * 4; d1.steps0 = D_DIM / 32;
        d1.totalSteps = D_DIM / 32;
        mfma_gemm<1><<<dim3(F_DIM / BMN, (F_DIM / BMN) * NUP), 256, 0, stream>>>(
            d1, nullptr, 0, vp, nullptr, conn, flag);
    }

    // G2 merged: approx = [x | uf_i...] @ [W_encT ; v_i...]^T + bias2
    {
        SegDesc d2{};
        d2.a0 = xp;  d2.b0 = Wtp;
        d2.str0 = D_DIM * 4; d2.steps0 = D_DIM / 32;
        int total = D_DIM / 32;
        const f16* aseg[3]; const f16* bseg[3];
        for (int i = 0; i < NUP && i < 3; ++i) {
            aseg[i] = ufp + (size_t)i * BS * 2 * F_DIM;
            bseg[i] = vp  + (size_t)i * F_DIM * 2 * F_DIM;
            total += F_DIM / 32;
        }
        if (NUP >= 1) { d2.a1 = aseg[0]; d2.b1 = bseg[0];
                        d2.str1 = F_DIM * 4; d2.steps1 = F_DIM / 32; }
        if (NUP >= 2) { d2.a2 = aseg[1]; d2.b2 = bseg[1];
                        d2.str2 = F_DIM * 4; d2.steps2 = F_DIM / 32; }
        if (NUP >= 3) { d2.a3 = aseg[2]; d2.b3 = bseg[2];
                        d2.str3 = F_DIM * 4; d2.steps3 = F_DIM / 32; }
        d2.totalSteps = total;
        mfma_gemm<0><<<dim3(BS / BMN, F_DIM / BMN), 256, 0, stream>>>(
            d2, approx, F_DIM, nullptr, bias2, nullptr, flag);
    }

    topk_decode_kernel<<<BS, 256, 0, stream>>>(
        approx, W_dec, b_dec, kptr, (float*)d_out);
}